// Round 10
// baseline (180.181 us; speedup 1.0000x reference)
//
#include <hip/hip_runtime.h>
#include <hip/hip_bf16.h>

// WeightedSigLipLoss: N=8192 rows, C=6 classes, D=512 features.
// loss[n] = sum_m softplus(agree[n,m]*(t*sim[n,m]+b)) * w[n]/sum(w)
// sim   = normalize(features) @ normalize(features)^T  (symmetric, bf16 1-pass)
// agree = 2 * targets @ targets^T - 1  (K=32 hi/lo-packed MFMA, err ~1e-6)
// Round 10: r9 (161 us, best) + merged last-block final WITHOUT __threadfence.
// r8's 210-us regression fingerprinted the fence (WRITE_SIZE doubled = L2
// writeback evicting co-resident blocks' panels). Ordering without fence:
// partial[] adds are device-scope atomic RMWs at the coherence point, and the
// compiler's __syncthreads() emits s_waitcnt vmcnt(0) (m97 asm) -> all this
// block's RMWs COMPLETED before lane0 bumps the counter; the last block reads
// partial via atomicAdd(p,0) RMWs at the same coherence point.

#define NROW 8192
#define DIM  512
#define NCLS 6

#define BM 128
#define BK 64
#define NB (NROW / BM)           // 64 block-rows
#define NTRI (NB * (NB + 1) / 2) // 2080 upper-tri blocks = 8 * 260 (bijective swizzle)
#define NSTG 8                   // 8 K-chunks of 64 (K=512)

typedef short s16x8 __attribute__((ext_vector_type(8)));
typedef float f32x4 __attribute__((ext_vector_type(4)));

static __device__ __forceinline__ ushort f2bf(float x) {
    __hip_bfloat16 h = __float2bfloat16(x);
    union { __hip_bfloat16 h; ushort u; } c; c.h = h; return c.u;
}
static __device__ __forceinline__ float bf2f(ushort u) {
    union { __hip_bfloat16 h; ushort u; } c; c.u = u; return __bfloat162float(c.h);
}

// ---------------- kernel 1: normalize + bf16 + target hi/lo pack + wsum parts ----------------
// fpack[n][512] bf16.  tpA/tpB[n][32] bf16 K=32 agree pack:
//   tpA k: [hi(6) | lo(6) | hi(6) | 0...]   tpB k: [hi(6) | hi(6) | lo(6) | 0...]
// one 16x16x32 MFMA = hi.hi + lo.hi + hi.lo  (exact to ~1e-6).
__global__ __launch_bounds__(256) void k_prep(const float* __restrict__ feat,
                                              const float* __restrict__ tgt,
                                              const float* __restrict__ w,
                                              ushort* __restrict__ fpack,
                                              ushort* __restrict__ tpA,
                                              ushort* __restrict__ tpB,
                                              float* __restrict__ partial,
                                              float* __restrict__ wpart,
                                              unsigned* __restrict__ counter) {
    const int wave = threadIdx.x >> 6, lane = threadIdx.x & 63;
    const int row = blockIdx.x * 4 + wave;
    const float* fr = feat + (size_t)row * DIM;
    float4 v0 = *(const float4*)(fr + lane * 4);
    float4 v1 = *(const float4*)(fr + 256 + lane * 4);
    float ss = v0.x*v0.x + v0.y*v0.y + v0.z*v0.z + v0.w*v0.w
             + v1.x*v1.x + v1.y*v1.y + v1.z*v1.z + v1.w*v1.w;
#pragma unroll
    for (int m = 1; m < 64; m <<= 1) ss += __shfl_xor(ss, m);
    const float inv = 1.f / fmaxf(sqrtf(ss), 1e-12f);

    float vals[8] = {v0.x, v0.y, v0.z, v0.w, v1.x, v1.y, v1.z, v1.w};
    ushort hi[8];
#pragma unroll
    for (int i = 0; i < 8; ++i) hi[i] = f2bf(vals[i] * inv);
    ushort* dst = fpack + (size_t)row * 512;
    *(ushort4*)(dst + lane * 4)       = make_ushort4(hi[0], hi[1], hi[2], hi[3]);
    *(ushort4*)(dst + 256 + lane * 4) = make_ushort4(hi[4], hi[5], hi[6], hi[7]);

    // target K=32 pack: lane == k slot
    if (lane < 32) {
        float ta = 0.f, tb = 0.f;
        if (lane < 18) {
            int c = (lane < 6) ? lane : (lane < 12 ? lane - 6 : lane - 12);
            float x = tgt[(size_t)row * NCLS + c];
            ushort h = f2bf(x);
            float hf = bf2f(h);
            float l = x - hf;
            if (lane < 6)       { ta = hf; tb = hf; }
            else if (lane < 12) { ta = l;  tb = hf; }
            else                { ta = hf; tb = l;  }
        }
        tpA[(size_t)row * 32 + lane] = f2bf(ta);
        tpB[(size_t)row * 32 + lane] = f2bf(tb);
    }

    __shared__ float red[4];
    if (lane == 0) {
        partial[row] = 0.f;
        red[wave] = w[row];
    }
    __syncthreads();
    if (threadIdx.x == 0) {
        wpart[blockIdx.x] = red[0] + red[1] + red[2] + red[3];
        if (blockIdx.x == 0) *counter = 0u;
    }
}

// ---------------- staging via global_load_lds (16B), linear LDS dest [G21] ----------------
// 128 rows x 64 bf16 (src stride 512): 1024 chunks of 16B, 256 threads x 4.
__device__ __forceinline__ void stage_f(const ushort* __restrict__ src,
                                        ushort* lds, int tid) {
#pragma unroll
    for (int i = 0; i < 4; ++i) {
        int q = i * 256 + tid;
        int r = q >> 3, c = q & 7;
        __builtin_amdgcn_global_load_lds(
            (const __attribute__((address_space(1))) void*)(src + (size_t)r * 512 + c * 8),
            (__attribute__((address_space(3))) void*)(lds + q * 8),
            16, 0, 0);
    }
}
// 128 rows x 32 bf16 (src stride 32): 512 chunks of 16B, 256 threads x 2.
__device__ __forceinline__ void stage_t(const ushort* __restrict__ src,
                                        ushort* lds, int tid) {
#pragma unroll
    for (int i = 0; i < 2; ++i) {
        int q = i * 256 + tid;
        int r = q >> 2, c = q & 3;
        __builtin_amdgcn_global_load_lds(
            (const __attribute__((address_space(1))) void*)(src + (size_t)r * 32 + c * 8),
            (__attribute__((address_space(3))) void*)(lds + q * 8),
            16, 0, 0);
    }
}

// ---------------- kernel 2: fused upper-tri GEMM + softplus + final (fence-free) ----------------
// r3/r9-proven loop: stage -> sync -> 32 MFMA -> sync, 8 stages (BK=64), then
// K=32 agree stage into the same sA/sB. 128x128 tile, 4 waves (2x2).
__global__ __launch_bounds__(256, 3) void k_gemm(
    const ushort* __restrict__ fpack, const ushort* __restrict__ tpA,
    const ushort* __restrict__ tpB, const float* __restrict__ tp,
    const float* __restrict__ bp, const float* __restrict__ w,
    float* __restrict__ partial, const float* __restrict__ wpart,
    unsigned* __restrict__ counter, float* __restrict__ out) {

    // bijective XCD swizzle (T1): NTRI = 8*260
    const int orig = blockIdx.x;
    const int b = (orig & 7) * (NTRI / 8) + (orig >> 3);
    // linear index -> upper-tri (bi, bj)
    int bi = 0, rem = b;
    while (rem >= NB - bi) { rem -= NB - bi; ++bi; }
    const int bj = bi + rem;

    __shared__ ushort sA[BM * BK];   // 16 KB
    __shared__ ushort sB[BM * BK];   // 16 KB

    const int tid = threadIdx.x;
    const int lane = tid & 63;
    const int wave = tid >> 6;
    const int wr = wave >> 1, wc = wave & 1;   // 2x2 waves, 64x64 each

    const float tt = *tp, bb = *bp;

    f32x4 accS[4][4], accT[4][4];
#pragma unroll
    for (int i = 0; i < 4; ++i)
#pragma unroll
        for (int j = 0; j < 4; ++j) {
            accS[i][j] = (f32x4){0.f, 0.f, 0.f, 0.f};
            accT[i][j] = (f32x4){0.f, 0.f, 0.f, 0.f};
        }

    const ushort* baseA = fpack + (size_t)(bi * BM) * 512;
    const ushort* baseB = fpack + (size_t)(bj * BM) * 512;

    for (int s = 0; s < NSTG; ++s) {
        stage_f(baseA + s * 64, &sA[0], tid);
        stage_f(baseB + s * 64, &sB[0], tid);
        __syncthreads();
#pragma unroll
        for (int kk = 0; kk < 2; ++kk) {
            s16x8 af[4], bg[4];
            const int kb = kk * 32 + (lane >> 4) * 8;
            const int rr = lane & 15;
#pragma unroll
            for (int i = 0; i < 4; ++i)
                af[i] = *(const s16x8*)(&sA[(wr * 64 + i * 16 + rr) * BK + kb]);
#pragma unroll
            for (int j = 0; j < 4; ++j)
                bg[j] = *(const s16x8*)(&sB[(wc * 64 + j * 16 + rr) * BK + kb]);
#pragma unroll
            for (int i = 0; i < 4; ++i)
#pragma unroll
                for (int j = 0; j < 4; ++j)
                    accS[i][j] = __builtin_amdgcn_mfma_f32_16x16x32_bf16(
                        af[i], bg[j], accS[i][j], 0, 0, 0);
        }
        __syncthreads();
    }

    // ---- agree stage: K=32 target pack ----
    stage_t(tpA + (size_t)(bi * BM) * 32, &sA[0], tid);
    stage_t(tpB + (size_t)(bj * BM) * 32, &sB[0], tid);
    __syncthreads();
    {
        s16x8 af[4], bg[4];
        const int kb = (lane >> 4) * 8;
        const int rr = lane & 15;
#pragma unroll
        for (int i = 0; i < 4; ++i)
            af[i] = *(const s16x8*)(&sA[(wr * 64 + i * 16 + rr) * 32 + kb]);
#pragma unroll
        for (int j = 0; j < 4; ++j)
            bg[j] = *(const s16x8*)(&sB[(wc * 64 + j * 16 + rr) * 32 + kb]);
#pragma unroll
        for (int i = 0; i < 4; ++i)
#pragma unroll
            for (int j = 0; j < 4; ++j)
                accT[i][j] = __builtin_amdgcn_mfma_f32_16x16x32_bf16(
                    af[i], bg[j], accT[i][j], 0, 0, 0);
    }

    // ---- epilogue: agree + softplus + row/col partial sums ----
    // C/D layout (m89): col = lane&15, row = (lane>>4)*4 + r
    float rowsum[4][4];
    float colsum[4];
#pragma unroll
    for (int i = 0; i < 4; ++i)
#pragma unroll
        for (int r = 0; r < 4; ++r) rowsum[i][r] = 0.f;
#pragma unroll
    for (int j = 0; j < 4; ++j) colsum[j] = 0.f;

#pragma unroll
    for (int i = 0; i < 4; ++i)
#pragma unroll
        for (int j = 0; j < 4; ++j)
#pragma unroll
            for (int r = 0; r < 4; ++r) {
                const float agree = fmaf(2.f, accT[i][j][r], -1.f);
                const float e = agree * fmaf(tt, accS[i][j][r], bb);
                // softplus(e), stable: max(e,0) + log(1+exp(-|e|))
                const float sp = fmaxf(e, 0.f) + __logf(1.f + __expf(-fabsf(e)));
                rowsum[i][r] += sp;
                colsum[j] += sp;
            }

    // row sums: reduce across the 16 col-lanes (bits 0..3)
#pragma unroll
    for (int i = 0; i < 4; ++i)
#pragma unroll
        for (int r = 0; r < 4; ++r) {
            float v = rowsum[i][r];
            v += __shfl_xor(v, 1); v += __shfl_xor(v, 2);
            v += __shfl_xor(v, 4); v += __shfl_xor(v, 8);
            if ((lane & 15) == 0)
                atomicAdd(&partial[bi * BM + wr * 64 + i * 16 + (lane >> 4) * 4 + r], v);
        }
    // col sums (transpose contribution), off-diagonal blocks only
    if (bi != bj) {
#pragma unroll
        for (int j = 0; j < 4; ++j) {
            float v = colsum[j];
            v += __shfl_xor(v, 16); v += __shfl_xor(v, 32);
            if (lane < 16)
                atomicAdd(&partial[bj * BM + wc * 64 + j * 16 + lane], v);
        }
    }

    // ---- last-block-done final scale, NO threadfence ----
    // __syncthreads() drains vmcnt(0) (compiler-emitted) => this block's
    // partial[] atomic RMWs have COMPLETED at the coherence point before
    // lane 0 increments the counter. No L2 writeback needed (r8's poison).
    __syncthreads();
    __shared__ bool sLast;
    if (tid == 0)
        sLast = (atomicAdd(counter, 1u) == NTRI - 1);
    __syncthreads();
    if (sLast) {
        __shared__ float red[4];
        float s = 0.f;
        for (int i = tid; i < NROW / 4; i += 256) s += wpart[i];
#pragma unroll
        for (int m = 1; m < 64; m <<= 1) s += __shfl_xor(s, m);
        if ((tid & 63) == 0) red[tid >> 6] = s;
        __syncthreads();
        const float wsum = red[0] + red[1] + red[2] + red[3];
        // read partial via atomic RMW (same coherence point as the adds)
        for (int i = tid; i < NROW; i += 256)
            out[i] = atomicAdd(&partial[i], 0.f) * w[i] / wsum;
    }
}

extern "C" void kernel_launch(void* const* d_in, const int* in_sizes, int n_in,
                              void* d_out, int out_size, void* d_ws, size_t ws_size,
                              hipStream_t stream) {
    // inputs: 0=logits(unused), 1=targets, 2=features, 3=weights, 4=t, 5=b
    const float* targets  = (const float*)d_in[1];
    const float* features = (const float*)d_in[2];
    const float* weights  = (const float*)d_in[3];
    const float* tp       = (const float*)d_in[4];
    const float* bp       = (const float*)d_in[5];
    float* out = (float*)d_out;

    // workspace layout (~9.1 MB)
    char* p = (char*)d_ws;
    ushort*   fpack   = (ushort*)p;   p += (size_t)NROW * 512 * sizeof(ushort); // 8 MB
    ushort*   tpA     = (ushort*)p;   p += (size_t)NROW * 32 * sizeof(ushort);  // 0.5 MB
    ushort*   tpB     = (ushort*)p;   p += (size_t)NROW * 32 * sizeof(ushort);  // 0.5 MB
    float*    partial = (float*)p;    p += (size_t)NROW * sizeof(float);        // 32 KB
    float*    wpart   = (float*)p;    p += (size_t)(NROW / 4) * sizeof(float);  // 8 KB
    unsigned* counter = (unsigned*)p;

    k_prep<<<NROW / 4, 256, 0, stream>>>(features, targets, weights, fpack, tpA, tpB,
                                         partial, wpart, counter);
    k_gemm<<<NTRI, 256, 0, stream>>>(fpack, tpA, tpB, tp, bp, weights,
                                     partial, wpart, counter, out);
}

// Round 11
// 153.449 us; speedup vs baseline: 1.1742x; 1.1742x over previous
//
#include <hip/hip_runtime.h>
#include <hip/hip_bf16.h>

// WeightedSigLipLoss: N=8192 rows, C=6 classes, D=512 features.
// loss[n] = sum_m softplus(agree[n,m]*(t*sim[n,m]+b)) * w[n]/sum(w)
// sim   = normalize(features) @ normalize(features)^T  (symmetric, bf16 1-pass)
// agree = 2 * targets @ targets^T - 1  (K=32 hi/lo-packed MFMA, err ~1e-6)
// Round 11: r9 (161 us best; 3 dispatches — merged-final abandoned after
// r6/r8/r10 all dilated k_gemm) + SUPERTILE block order. r9's FETCH=75MB
// fingerprint: each XCD chunk spanned the full bj range -> 8.5MB B-panels
// thrash the 4MB per-XCD L2 -> every stage drain pays L3 latency. 8x8-block
// supertiles keep the concurrent working set (~8 A + ~16 B panels ~ 3MB)
// L2-resident. Pure index permutation; k_gemm otherwise r9-verbatim.

#define NROW 8192
#define DIM  512
#define NCLS 6

#define BM 128
#define BK 64
#define NB (NROW / BM)           // 64 block-rows
#define NTRI (NB * (NB + 1) / 2) // 2080 upper-tri blocks = 8 * 260 (XCD chunks)
#define NSTG 8                   // 8 K-chunks of 64 (K=512)

typedef short s16x8 __attribute__((ext_vector_type(8)));
typedef float f32x4 __attribute__((ext_vector_type(4)));

static __device__ __forceinline__ ushort f2bf(float x) {
    __hip_bfloat16 h = __float2bfloat16(x);
    union { __hip_bfloat16 h; ushort u; } c; c.h = h; return c.u;
}
static __device__ __forceinline__ float bf2f(ushort u) {
    union { __hip_bfloat16 h; ushort u; } c; c.u = u; return __bfloat162float(c.h);
}

// ---------------- kernel 1: normalize + bf16 + target hi/lo pack + wsum parts ----------------
// fpack[n][512] bf16.  tpA/tpB[n][32] bf16 K=32 agree pack:
//   tpA k: [hi(6) | lo(6) | hi(6) | 0...]   tpB k: [hi(6) | hi(6) | lo(6) | 0...]
// one 16x16x32 MFMA = hi.hi + lo.hi + hi.lo  (exact to ~1e-6).
__global__ __launch_bounds__(256) void k_prep(const float* __restrict__ feat,
                                              const float* __restrict__ tgt,
                                              const float* __restrict__ w,
                                              ushort* __restrict__ fpack,
                                              ushort* __restrict__ tpA,
                                              ushort* __restrict__ tpB,
                                              float* __restrict__ partial,
                                              float* __restrict__ wpart) {
    const int wave = threadIdx.x >> 6, lane = threadIdx.x & 63;
    const int row = blockIdx.x * 4 + wave;
    const float* fr = feat + (size_t)row * DIM;
    float4 v0 = *(const float4*)(fr + lane * 4);
    float4 v1 = *(const float4*)(fr + 256 + lane * 4);
    float ss = v0.x*v0.x + v0.y*v0.y + v0.z*v0.z + v0.w*v0.w
             + v1.x*v1.x + v1.y*v1.y + v1.z*v1.z + v1.w*v1.w;
#pragma unroll
    for (int m = 1; m < 64; m <<= 1) ss += __shfl_xor(ss, m);
    const float inv = 1.f / fmaxf(sqrtf(ss), 1e-12f);

    float vals[8] = {v0.x, v0.y, v0.z, v0.w, v1.x, v1.y, v1.z, v1.w};
    ushort hi[8];
#pragma unroll
    for (int i = 0; i < 8; ++i) hi[i] = f2bf(vals[i] * inv);
    ushort* dst = fpack + (size_t)row * 512;
    *(ushort4*)(dst + lane * 4)       = make_ushort4(hi[0], hi[1], hi[2], hi[3]);
    *(ushort4*)(dst + 256 + lane * 4) = make_ushort4(hi[4], hi[5], hi[6], hi[7]);

    // target K=32 pack: lane == k slot
    if (lane < 32) {
        float ta = 0.f, tb = 0.f;
        if (lane < 18) {
            int c = (lane < 6) ? lane : (lane < 12 ? lane - 6 : lane - 12);
            float x = tgt[(size_t)row * NCLS + c];
            ushort h = f2bf(x);
            float hf = bf2f(h);
            float l = x - hf;
            if (lane < 6)       { ta = hf; tb = hf; }
            else if (lane < 12) { ta = l;  tb = hf; }
            else                { ta = hf; tb = l;  }
        }
        tpA[(size_t)row * 32 + lane] = f2bf(ta);
        tpB[(size_t)row * 32 + lane] = f2bf(tb);
    }

    __shared__ float red[4];
    if (lane == 0) {
        partial[row] = 0.f;
        red[wave] = w[row];
    }
    __syncthreads();
    if (threadIdx.x == 0)
        wpart[blockIdx.x] = red[0] + red[1] + red[2] + red[3];
}

// ---------------- staging via global_load_lds (16B), linear LDS dest [G21] ----------------
// 128 rows x 64 bf16 (src stride 512): 1024 chunks of 16B, 256 threads x 4.
__device__ __forceinline__ void stage_f(const ushort* __restrict__ src,
                                        ushort* lds, int tid) {
#pragma unroll
    for (int i = 0; i < 4; ++i) {
        int q = i * 256 + tid;
        int r = q >> 3, c = q & 7;
        __builtin_amdgcn_global_load_lds(
            (const __attribute__((address_space(1))) void*)(src + (size_t)r * 512 + c * 8),
            (__attribute__((address_space(3))) void*)(lds + q * 8),
            16, 0, 0);
    }
}
// 128 rows x 32 bf16 (src stride 32): 512 chunks of 16B, 256 threads x 2.
__device__ __forceinline__ void stage_t(const ushort* __restrict__ src,
                                        ushort* lds, int tid) {
#pragma unroll
    for (int i = 0; i < 2; ++i) {
        int q = i * 256 + tid;
        int r = q >> 2, c = q & 3;
        __builtin_amdgcn_global_load_lds(
            (const __attribute__((address_space(1))) void*)(src + (size_t)r * 32 + c * 8),
            (__attribute__((address_space(3))) void*)(lds + q * 8),
            16, 0, 0);
    }
}

// ---------------- kernel 2: fused upper-tri GEMM + softplus reduction (r9 loop) ----------------
// Single-buffer: stage -> sync -> 32 MFMA -> sync, 8 stages (BK=64), then
// K=32 agree stage into the same sA/sB. 128x128 tile, 4 waves (2x2).
__global__ __launch_bounds__(256, 3) void k_gemm(
    const ushort* __restrict__ fpack, const ushort* __restrict__ tpA,
    const ushort* __restrict__ tpB, const float* __restrict__ tp,
    const float* __restrict__ bp, float* __restrict__ partial) {

    // ---- supertile-major decode + XCD chunk swizzle ----
    // XCD chunk (T1): consecutive logical b per XCD.
    const int orig = blockIdx.x;
    int b = (orig & 7) * (NTRI / 8) + (orig >> 3);
    // b enumerates 8x8-block supertiles: per SI row: diag(36 blocks) then
    // off-diag supertiles (SI,SJ), SJ>SI, 64 blocks each (row-major inside).
    int SI = 0, rem = b;
    while (rem >= 36 + (7 - SI) * 64) { rem -= 36 + (7 - SI) * 64; ++SI; }
    int bi, bj;
    if (rem < 36) {                       // diagonal supertile (SI,SI)
        int ii = 0;
        while (rem >= 8 - ii) { rem -= 8 - ii; ++ii; }
        bi = SI * 8 + ii;
        bj = SI * 8 + ii + rem;
    } else {                              // off-diagonal supertile (SI,SJ)
        const int r2 = rem - 36;
        const int SJ = SI + 1 + (r2 >> 6);
        const int idx = r2 & 63;
        bi = SI * 8 + (idx >> 3);
        bj = SJ * 8 + (idx & 7);
    }

    __shared__ ushort sA[BM * BK];   // 16 KB
    __shared__ ushort sB[BM * BK];   // 16 KB

    const int tid = threadIdx.x;
    const int lane = tid & 63;
    const int wave = tid >> 6;
    const int wr = wave >> 1, wc = wave & 1;   // 2x2 waves, 64x64 each

    const float tt = *tp, bb = *bp;

    f32x4 accS[4][4], accT[4][4];
#pragma unroll
    for (int i = 0; i < 4; ++i)
#pragma unroll
        for (int j = 0; j < 4; ++j) {
            accS[i][j] = (f32x4){0.f, 0.f, 0.f, 0.f};
            accT[i][j] = (f32x4){0.f, 0.f, 0.f, 0.f};
        }

    const ushort* baseA = fpack + (size_t)(bi * BM) * 512;
    const ushort* baseB = fpack + (size_t)(bj * BM) * 512;

    for (int s = 0; s < NSTG; ++s) {
        stage_f(baseA + s * 64, &sA[0], tid);
        stage_f(baseB + s * 64, &sB[0], tid);
        __syncthreads();
#pragma unroll
        for (int kk = 0; kk < 2; ++kk) {
            s16x8 af[4], bg[4];
            const int kb = kk * 32 + (lane >> 4) * 8;
            const int rr = lane & 15;
#pragma unroll
            for (int i = 0; i < 4; ++i)
                af[i] = *(const s16x8*)(&sA[(wr * 64 + i * 16 + rr) * BK + kb]);
#pragma unroll
            for (int j = 0; j < 4; ++j)
                bg[j] = *(const s16x8*)(&sB[(wc * 64 + j * 16 + rr) * BK + kb]);
#pragma unroll
            for (int i = 0; i < 4; ++i)
#pragma unroll
                for (int j = 0; j < 4; ++j)
                    accS[i][j] = __builtin_amdgcn_mfma_f32_16x16x32_bf16(
                        af[i], bg[j], accS[i][j], 0, 0, 0);
        }
        __syncthreads();
    }

    // ---- agree stage: K=32 target pack ----
    stage_t(tpA + (size_t)(bi * BM) * 32, &sA[0], tid);
    stage_t(tpB + (size_t)(bj * BM) * 32, &sB[0], tid);
    __syncthreads();
    {
        s16x8 af[4], bg[4];
        const int kb = (lane >> 4) * 8;
        const int rr = lane & 15;
#pragma unroll
        for (int i = 0; i < 4; ++i)
            af[i] = *(const s16x8*)(&sA[(wr * 64 + i * 16 + rr) * 32 + kb]);
#pragma unroll
        for (int j = 0; j < 4; ++j)
            bg[j] = *(const s16x8*)(&sB[(wc * 64 + j * 16 + rr) * 32 + kb]);
#pragma unroll
        for (int i = 0; i < 4; ++i)
#pragma unroll
            for (int j = 0; j < 4; ++j)
                accT[i][j] = __builtin_amdgcn_mfma_f32_16x16x32_bf16(
                    af[i], bg[j], accT[i][j], 0, 0, 0);
    }

    // ---- epilogue: agree + softplus + row/col partial sums ----
    // C/D layout (m89): col = lane&15, row = (lane>>4)*4 + r
    float rowsum[4][4];
    float colsum[4];
#pragma unroll
    for (int i = 0; i < 4; ++i)
#pragma unroll
        for (int r = 0; r < 4; ++r) rowsum[i][r] = 0.f;
#pragma unroll
    for (int j = 0; j < 4; ++j) colsum[j] = 0.f;

#pragma unroll
    for (int i = 0; i < 4; ++i)
#pragma unroll
        for (int j = 0; j < 4; ++j)
#pragma unroll
            for (int r = 0; r < 4; ++r) {
                const float agree = fmaf(2.f, accT[i][j][r], -1.f);
                const float e = agree * fmaf(tt, accS[i][j][r], bb);
                // softplus(e), stable: max(e,0) + log(1+exp(-|e|))
                const float sp = fmaxf(e, 0.f) + __logf(1.f + __expf(-fabsf(e)));
                rowsum[i][r] += sp;
                colsum[j] += sp;
            }

    // row sums: reduce across the 16 col-lanes (bits 0..3)
#pragma unroll
    for (int i = 0; i < 4; ++i)
#pragma unroll
        for (int r = 0; r < 4; ++r) {
            float v = rowsum[i][r];
            v += __shfl_xor(v, 1); v += __shfl_xor(v, 2);
            v += __shfl_xor(v, 4); v += __shfl_xor(v, 8);
            if ((lane & 15) == 0)
                atomicAdd(&partial[bi * BM + wr * 64 + i * 16 + (lane >> 4) * 4 + r], v);
        }
    // col sums (transpose contribution), off-diagonal blocks only
    if (bi != bj) {
#pragma unroll
        for (int j = 0; j < 4; ++j) {
            float v = colsum[j];
            v += __shfl_xor(v, 16); v += __shfl_xor(v, 32);
            if (lane < 16)
                atomicAdd(&partial[bj * BM + wc * 64 + j * 16 + lane], v);
        }
    }
}

// ---------------- kernel 3: wsum reduce + final scale ----------------
// loss[n] = (1/N)*rowsum[n] * w[n] / (wsum/N) = rowsum[n] * w[n] / wsum
__global__ __launch_bounds__(256) void k_final(const float* __restrict__ partial,
                                               const float* __restrict__ w,
                                               const float* __restrict__ wpart,
                                               float* __restrict__ out) {
    __shared__ float red[4];
    float s = 0.f;
    for (int i = threadIdx.x; i < NROW / 4; i += 256) s += wpart[i];
#pragma unroll
    for (int m = 1; m < 64; m <<= 1) s += __shfl_xor(s, m);
    if ((threadIdx.x & 63) == 0) red[threadIdx.x >> 6] = s;
    __syncthreads();
    const float wsum = red[0] + red[1] + red[2] + red[3];
    int i = blockIdx.x * 256 + threadIdx.x;
    out[i] = partial[i] * w[i] / wsum;
}

extern "C" void kernel_launch(void* const* d_in, const int* in_sizes, int n_in,
                              void* d_out, int out_size, void* d_ws, size_t ws_size,
                              hipStream_t stream) {
    // inputs: 0=logits(unused), 1=targets, 2=features, 3=weights, 4=t, 5=b
    const float* targets  = (const float*)d_in[1];
    const float* features = (const float*)d_in[2];
    const float* weights  = (const float*)d_in[3];
    const float* tp       = (const float*)d_in[4];
    const float* bp       = (const float*)d_in[5];
    float* out = (float*)d_out;

    // workspace layout (~9.1 MB)
    char* p = (char*)d_ws;
    ushort* fpack   = (ushort*)p; p += (size_t)NROW * 512 * sizeof(ushort); // 8 MB
    ushort* tpA     = (ushort*)p; p += (size_t)NROW * 32 * sizeof(ushort);  // 0.5 MB
    ushort* tpB     = (ushort*)p; p += (size_t)NROW * 32 * sizeof(ushort);  // 0.5 MB
    float*  partial = (float*)p;  p += (size_t)NROW * sizeof(float);        // 32 KB
    float*  wpart   = (float*)p;  p += (size_t)(NROW / 4) * sizeof(float);  // 8 KB

    k_prep<<<NROW / 4, 256, 0, stream>>>(features, targets, weights, fpack, tpA, tpB,
                                         partial, wpart);
    k_gemm<<<NTRI, 256, 0, stream>>>(fpack, tpA, tpB, tp, bp, partial);
    k_final<<<NROW / 256, 256, 0, stream>>>(partial, weights, wpart, out);
}

// Round 12
// 148.994 us; speedup vs baseline: 1.2093x; 1.0299x over previous
//
#include <hip/hip_runtime.h>
#include <hip/hip_bf16.h>

// WeightedSigLipLoss: N=8192 rows, C=6 classes, D=512 features.
// loss[n] = sum_m softplus(agree[n,m]*(t*sim[n,m]+b)) * w[n]/sum(w)
// sim   = normalize(features) @ normalize(features)^T  (symmetric, bf16 1-pass)
// agree = 2 * targets @ targets^T - 1  (K=32 hi/lo-packed MFMA, err ~1e-6)
// Round 12: r11 (153 us best: supertile order, FETCH 75->29MB) +
//  (a) T4 counted-vmcnt double-buffer: 4 compile-time-distinct LDS buffers,
//      raw s_barrier + asm vmcnt(8) (never 0 in loop) -> next stage's loads
//      fly during MFMA. r4's failure was __syncthreads' implicit vmcnt(0).
//  (b) T2 swizzle via G21 pre-swizzled-global: k_prep writes fpack chunks at
//      offset ^ ((row&7)<<3); k_gemm reads at kb ^ ((lane&7)<<3). Kills the
//      16-way bank conflict (row-stride 128B, G4) = 1.3e7 extra LDS cycles.
//  Catalog says (a) and (b) only pay together (T2 gated by pipelining, m252).

#define NROW 8192
#define DIM  512
#define NCLS 6

#define BM 128
#define BK 64
#define NB (NROW / BM)           // 64 block-rows
#define NTRI (NB * (NB + 1) / 2) // 2080 upper-tri blocks = 8 * 260 (XCD chunks)

typedef short s16x8 __attribute__((ext_vector_type(8)));
typedef float f32x4 __attribute__((ext_vector_type(4)));

static __device__ __forceinline__ ushort f2bf(float x) {
    __hip_bfloat16 h = __float2bfloat16(x);
    union { __hip_bfloat16 h; ushort u; } c; c.h = h; return c.u;
}
static __device__ __forceinline__ float bf2f(ushort u) {
    union { __hip_bfloat16 h; ushort u; } c; c.u = u; return __bfloat162float(c.h);
}

// ---------------- kernel 1: normalize + bf16 (chunk-swizzled) + target pack + wsum ----------------
// fpack[n][512] bf16, 16B chunks within each row stored at chunkpos ^ (row&7)
// (XOR on element-offset bits 3..5). After linear global_load_lds staging,
// LDS holds the swizzled tile; reads XOR the same key -> conflict-free.
__global__ __launch_bounds__(256) void k_prep(const float* __restrict__ feat,
                                              const float* __restrict__ tgt,
                                              const float* __restrict__ w,
                                              ushort* __restrict__ fpack,
                                              ushort* __restrict__ tpA,
                                              ushort* __restrict__ tpB,
                                              float* __restrict__ partial,
                                              float* __restrict__ wpart) {
    const int wave = threadIdx.x >> 6, lane = threadIdx.x & 63;
    const int row = blockIdx.x * 4 + wave;
    const float* fr = feat + (size_t)row * DIM;
    float4 v0 = *(const float4*)(fr + lane * 4);
    float4 v1 = *(const float4*)(fr + 256 + lane * 4);
    float ss = v0.x*v0.x + v0.y*v0.y + v0.z*v0.z + v0.w*v0.w
             + v1.x*v1.x + v1.y*v1.y + v1.z*v1.z + v1.w*v1.w;
#pragma unroll
    for (int m = 1; m < 64; m <<= 1) ss += __shfl_xor(ss, m);
    const float inv = 1.f / fmaxf(sqrtf(ss), 1e-12f);

    float vals[8] = {v0.x, v0.y, v0.z, v0.w, v1.x, v1.y, v1.z, v1.w};
    ushort hi[8];
#pragma unroll
    for (int i = 0; i < 8; ++i) hi[i] = f2bf(vals[i] * inv);
    ushort* dst = fpack + (size_t)row * 512;
    const int sw = (row & 7) << 3;           // XOR key on elem-offset bits 3..5
    *(ushort4*)(dst + ((lane * 4) ^ sw))         = make_ushort4(hi[0], hi[1], hi[2], hi[3]);
    *(ushort4*)(dst + ((256 + lane * 4) ^ sw))   = make_ushort4(hi[4], hi[5], hi[6], hi[7]);

    // target K=32 pack (kept LINEAR): lane == k slot
    if (lane < 32) {
        float ta = 0.f, tb = 0.f;
        if (lane < 18) {
            int c = (lane < 6) ? lane : (lane < 12 ? lane - 6 : lane - 12);
            float x = tgt[(size_t)row * NCLS + c];
            ushort h = f2bf(x);
            float hf = bf2f(h);
            float l = x - hf;
            if (lane < 6)       { ta = hf; tb = hf; }
            else if (lane < 12) { ta = l;  tb = hf; }
            else                { ta = hf; tb = l;  }
        }
        tpA[(size_t)row * 32 + lane] = f2bf(ta);
        tpB[(size_t)row * 32 + lane] = f2bf(tb);
    }

    __shared__ float red[4];
    if (lane == 0) {
        partial[row] = 0.f;
        red[wave] = w[row];
    }
    __syncthreads();
    if (threadIdx.x == 0)
        wpart[blockIdx.x] = red[0] + red[1] + red[2] + red[3];
}

// ---------------- staging via global_load_lds (16B), linear LDS dest [G21] ----------------
// 128 rows x 64 bf16 (src stride 512): 1024 chunks of 16B, 256 threads x 4. 8 vmem/thread... (4/thread here; A+B = 8)
__device__ __forceinline__ void stage_f(const ushort* __restrict__ src,
                                        ushort* lds, int tid) {
#pragma unroll
    for (int i = 0; i < 4; ++i) {
        int q = i * 256 + tid;
        int r = q >> 3, c = q & 7;
        __builtin_amdgcn_global_load_lds(
            (const __attribute__((address_space(1))) void*)(src + (size_t)r * 512 + c * 8),
            (__attribute__((address_space(3))) void*)(lds + q * 8),
            16, 0, 0);
    }
}
// 128 rows x 32 bf16 (src stride 32): 512 chunks of 16B, 256 threads x 2.
__device__ __forceinline__ void stage_t(const ushort* __restrict__ src,
                                        ushort* lds, int tid) {
#pragma unroll
    for (int i = 0; i < 2; ++i) {
        int q = i * 256 + tid;
        int r = q >> 2, c = q & 3;
        __builtin_amdgcn_global_load_lds(
            (const __attribute__((address_space(1))) void*)(src + (size_t)r * 32 + c * 8),
            (__attribute__((address_space(3))) void*)(lds + q * 8),
            16, 0, 0);
    }
}

// ---------------- kernel 2: fused upper-tri GEMM + softplus reduction ----------------
// Counted-vmcnt double-buffer: stage(next)->vmcnt(8)->barrier->MFMA->barrier.
// Next stage's 8 global_load_lds stay in flight through the MFMA phase.
// 128x128 tile, 4 waves (2x2), 4x4 16x16x32 fragments; swizzled LDS reads.
__global__ __launch_bounds__(256, 2) void k_gemm(
    const ushort* __restrict__ fpack, const ushort* __restrict__ tpA,
    const ushort* __restrict__ tpB, const float* __restrict__ tp,
    const float* __restrict__ bp, float* __restrict__ partial) {

    // ---- supertile-major decode + XCD chunk swizzle (r11-proven) ----
    const int orig = blockIdx.x;
    int b = (orig & 7) * (NTRI / 8) + (orig >> 3);
    int SI = 0, rem = b;
    while (rem >= 36 + (7 - SI) * 64) { rem -= 36 + (7 - SI) * 64; ++SI; }
    int bi, bj;
    if (rem < 36) {                       // diagonal supertile (SI,SI)
        int ii = 0;
        while (rem >= 8 - ii) { rem -= 8 - ii; ++ii; }
        bi = SI * 8 + ii;
        bj = SI * 8 + ii + rem;
    } else {                              // off-diagonal supertile (SI,SJ)
        const int r2 = rem - 36;
        const int SJ = SI + 1 + (r2 >> 6);
        const int idx = r2 & 63;
        bi = SI * 8 + (idx >> 3);
        bj = SJ * 8 + (idx & 7);
    }

    // four compile-time-distinct LDS buffers (alias-analysis friendly)
    __shared__ __align__(16) ushort sA0[BM * BK];   // 16 KB
    __shared__ __align__(16) ushort sB0[BM * BK];
    __shared__ __align__(16) ushort sA1[BM * BK];
    __shared__ __align__(16) ushort sB1[BM * BK];

    const int tid = threadIdx.x;
    const int lane = tid & 63;
    const int wave = tid >> 6;
    const int wr = wave >> 1, wc = wave & 1;   // 2x2 waves, 64x64 each

    const float tt = *tp, bb = *bp;

    f32x4 accS[4][4], accT[4][4];
#pragma unroll
    for (int i = 0; i < 4; ++i)
#pragma unroll
        for (int j = 0; j < 4; ++j) {
            accS[i][j] = (f32x4){0.f, 0.f, 0.f, 0.f};
            accT[i][j] = (f32x4){0.f, 0.f, 0.f, 0.f};
        }

    const ushort* baseA = fpack + (size_t)(bi * BM) * 512;
    const ushort* baseB = fpack + (size_t)(bj * BM) * 512;
    const int rr = lane & 15;
    const int ksw = (lane & 7) << 3;          // read-side swizzle key (row&7 == lane&7)

// one K-stage of MFMA from buffers SA/SB (swizzled reads, conflict-free)
#define COMPUTE_SIM(SA, SB)                                                     \
    do {                                                                        \
        _Pragma("unroll")                                                       \
        for (int kk = 0; kk < 2; ++kk) {                                        \
            s16x8 af[4], bg[4];                                                 \
            const int kb = (kk * 32 + ((lane >> 4) * 8)) ^ ksw;                 \
            _Pragma("unroll")                                                   \
            for (int i = 0; i < 4; ++i)                                         \
                af[i] = *(const s16x8*)(&SA[(wr * 64 + i * 16 + rr) * BK + kb]);\
            _Pragma("unroll")                                                   \
            for (int j = 0; j < 4; ++j)                                         \
                bg[j] = *(const s16x8*)(&SB[(wc * 64 + j * 16 + rr) * BK + kb]);\
            _Pragma("unroll")                                                   \
            for (int i = 0; i < 4; ++i)                                         \
                _Pragma("unroll")                                               \
                for (int j = 0; j < 4; ++j)                                     \
                    accS[i][j] = __builtin_amdgcn_mfma_f32_16x16x32_bf16(       \
                        af[i], bg[j], accS[i][j], 0, 0, 0);                     \
        }                                                                       \
    } while (0)

#define PHASE_SYNC()                         \
    __builtin_amdgcn_s_barrier();            \
    __builtin_amdgcn_sched_barrier(0)

    // prologue: stage 0 into buf0
    stage_f(baseA, sA0, tid);
    stage_f(baseB, sB0, tid);

#pragma unroll
    for (int s = 0; s < 8; s += 2) {
        // stage s+1 into buf1 (8 loads in flight across the compute below)
        stage_f(baseA + (s + 1) * 64, sA1, tid);
        stage_f(baseB + (s + 1) * 64, sB1, tid);
        asm volatile("s_waitcnt vmcnt(8)" ::: "memory");  // buf0 ready, buf1 flying
        PHASE_SYNC();
        COMPUTE_SIM(sA0, sB0);
        PHASE_SYNC();                                     // all waves done reading buf0
        if (s + 2 < 8) {
            stage_f(baseA + (s + 2) * 64, sA0, tid);
            stage_f(baseB + (s + 2) * 64, sB0, tid);
            asm volatile("s_waitcnt vmcnt(8)" ::: "memory");
        } else {
            // 9th pipelined stage: targets (4 loads) into buf0
            stage_t(tpA + (size_t)(bi * BM) * 32, sA0, tid);
            stage_t(tpB + (size_t)(bj * BM) * 32, sB0, tid);
            asm volatile("s_waitcnt vmcnt(4)" ::: "memory");
        }
        PHASE_SYNC();                                     // buf1 ready
        COMPUTE_SIM(sA1, sB1);
        PHASE_SYNC();                                     // all waves done reading buf1
    }

    // ---- agree stage: K=32 target pack in sA0/sB0 (linear layout) ----
    asm volatile("s_waitcnt vmcnt(0)" ::: "memory");
    PHASE_SYNC();
    {
        s16x8 af[4], bg[4];
        const int kbt = (lane >> 4) * 8;
#pragma unroll
        for (int i = 0; i < 4; ++i)
            af[i] = *(const s16x8*)(&sA0[(wr * 64 + i * 16 + rr) * 32 + kbt]);
#pragma unroll
        for (int j = 0; j < 4; ++j)
            bg[j] = *(const s16x8*)(&sB0[(wc * 64 + j * 16 + rr) * 32 + kbt]);
#pragma unroll
        for (int i = 0; i < 4; ++i)
#pragma unroll
            for (int j = 0; j < 4; ++j)
                accT[i][j] = __builtin_amdgcn_mfma_f32_16x16x32_bf16(
                    af[i], bg[j], accT[i][j], 0, 0, 0);
    }

    // ---- epilogue: agree + softplus + row/col partial sums ----
    // C/D layout (m89): col = lane&15, row = (lane>>4)*4 + r
    float rowsum[4][4];
    float colsum[4];
#pragma unroll
    for (int i = 0; i < 4; ++i)
#pragma unroll
        for (int r = 0; r < 4; ++r) rowsum[i][r] = 0.f;
#pragma unroll
    for (int j = 0; j < 4; ++j) colsum[j] = 0.f;

#pragma unroll
    for (int i = 0; i < 4; ++i)
#pragma unroll
        for (int j = 0; j < 4; ++j)
#pragma unroll
            for (int r = 0; r < 4; ++r) {
                const float agree = fmaf(2.f, accT[i][j][r], -1.f);
                const float e = agree * fmaf(tt, accS[i][j][r], bb);
                // softplus(e), stable: max(e,0) + log(1+exp(-|e|))
                const float sp = fmaxf(e, 0.f) + __logf(1.f + __expf(-fabsf(e)));
                rowsum[i][r] += sp;
                colsum[j] += sp;
            }

    // row sums: reduce across the 16 col-lanes (bits 0..3)
#pragma unroll
    for (int i = 0; i < 4; ++i)
#pragma unroll
        for (int r = 0; r < 4; ++r) {
            float v = rowsum[i][r];
            v += __shfl_xor(v, 1); v += __shfl_xor(v, 2);
            v += __shfl_xor(v, 4); v += __shfl_xor(v, 8);
            if ((lane & 15) == 0)
                atomicAdd(&partial[bi * BM + wr * 64 + i * 16 + (lane >> 4) * 4 + r], v);
        }
    // col sums (transpose contribution), off-diagonal blocks only
    if (bi != bj) {
#pragma unroll
        for (int j = 0; j < 4; ++j) {
            float v = colsum[j];
            v += __shfl_xor(v, 16); v += __shfl_xor(v, 32);
            if (lane < 16)
                atomicAdd(&partial[bj * BM + wc * 64 + j * 16 + lane], v);
        }
    }
#undef COMPUTE_SIM
#undef PHASE_SYNC
}

// ---------------- kernel 3: wsum reduce + final scale ----------------
// loss[n] = (1/N)*rowsum[n] * w[n] / (wsum/N) = rowsum[n] * w[n] / wsum
__global__ __launch_bounds__(256) void k_final(const float* __restrict__ partial,
                                               const float* __restrict__ w,
                                               const float* __restrict__ wpart,
                                               float* __restrict__ out) {
    __shared__ float red[4];
    float s = 0.f;
    for (int i = threadIdx.x; i < NROW / 4; i += 256) s += wpart[i];
#pragma unroll
    for (int m = 1; m < 64; m <<= 1) s += __shfl_xor(s, m);
    if ((threadIdx.x & 63) == 0) red[threadIdx.x >> 6] = s;
    __syncthreads();
    const float wsum = red[0] + red[1] + red[2] + red[3];
    int i = blockIdx.x * 256 + threadIdx.x;
    out[i] = partial[i] * w[i] / wsum;
}

extern "C" void kernel_launch(void* const* d_in, const int* in_sizes, int n_in,
                              void* d_out, int out_size, void* d_ws, size_t ws_size,
                              hipStream_t stream) {
    // inputs: 0=logits(unused), 1=targets, 2=features, 3=weights, 4=t, 5=b
    const float* targets  = (const float*)d_in[1];
    const float* features = (const float*)d_in[2];
    const float* weights  = (const float*)d_in[3];
    const float* tp       = (const float*)d_in[4];
    const float* bp       = (const float*)d_in[5];
    float* out = (float*)d_out;

    // workspace layout (~9.1 MB)
    char* p = (char*)d_ws;
    ushort* fpack   = (ushort*)p; p += (size_t)NROW * 512 * sizeof(ushort); // 8 MB
    ushort* tpA     = (ushort*)p; p += (size_t)NROW * 32 * sizeof(ushort);  // 0.5 MB
    ushort* tpB     = (ushort*)p; p += (size_t)NROW * 32 * sizeof(ushort);  // 0.5 MB
    float*  partial = (float*)p;  p += (size_t)NROW * sizeof(float);        // 32 KB
    float*  wpart   = (float*)p;  p += (size_t)(NROW / 4) * sizeof(float);  // 8 KB

    k_prep<<<NROW / 4, 256, 0, stream>>>(features, targets, weights, fpack, tpA, tpB,
                                         partial, wpart);
    k_gemm<<<NTRI, 256, 0, stream>>>(fpack, tpA, tpB, tp, bp, partial);
    k_final<<<NROW / 256, 256, 0, stream>>>(partial, weights, wpart, out);
}